// Round 1
// baseline (542.886 us; speedup 1.0000x reference)
//
#include <hip/hip_runtime.h>
#include <math.h>

#define NN 20000          // nodes per graph
#define NE 320000         // edges (before self loops)
#define ETOT (NE + NN)    // edges + self loops
#define NH 4              // heads
#define CH 64             // channels per head
#define HC 256            // NH*CH
#define FIN 128           // layer-1 input features
#define NEG_SLOPE 0.2f

// ---------------- CSR build ----------------

__global__ void k_zero_i32(int* __restrict__ p, int n) {
    int i = blockIdx.x * blockDim.x + threadIdx.x;
    if (i < n) p[i] = 0;
}

__global__ void k_hist(const int* __restrict__ ei, int* __restrict__ counts) {
    int e = blockIdx.x * blockDim.x + threadIdx.x;
    if (e >= ETOT) return;
    int d = (e < NE) ? ei[NE + e] : (e - NE);
    atomicAdd(&counts[d], 1);
}

__global__ void k_scan(const int* __restrict__ counts, int* __restrict__ rowptr) {
    __shared__ int part[1024];
    int tid = threadIdx.x;
    const int n = NN;
    int chunk = (n + 1023) / 1024;
    int b = tid * chunk;
    int e = min(b + chunk, n);
    int s = 0;
    for (int i = b; i < e; ++i) s += counts[i];
    part[tid] = s;
    __syncthreads();
    for (int off = 1; off < 1024; off <<= 1) {
        int v = (tid >= off) ? part[tid - off] : 0;
        __syncthreads();
        part[tid] += v;
        __syncthreads();
    }
    int ex = (tid > 0) ? part[tid - 1] : 0;
    for (int i = b; i < e; ++i) { rowptr[i] = ex; ex += counts[i]; }
    if (tid == 1023) rowptr[n] = part[1023];
}

__global__ void k_copy_i32(const int* __restrict__ s, int* __restrict__ d, int n) {
    int i = blockIdx.x * blockDim.x + threadIdx.x;
    if (i < n) d[i] = s[i];
}

__global__ void k_scatter(const int* __restrict__ ei, int* __restrict__ cursor,
                          int* __restrict__ col) {
    int e = blockIdx.x * blockDim.x + threadIdx.x;
    if (e >= ETOT) return;
    int s, d;
    if (e < NE) { s = ei[e]; d = ei[NE + e]; }
    else        { s = e - NE; d = s; }
    int pos = atomicAdd(&cursor[d], 1);
    col[pos] = s;
}

// ---------------- fp32 tiled GEMM: C[M,NC] = A[M,K] @ B[K,NC] (+bias) ----------------
// 64x64 tile, 256 threads, 4x4 micro-tile, K multiple of 32, NC multiple of 64.

__global__ __launch_bounds__(256) void k_gemm(const float* __restrict__ A,
                                              const float* __restrict__ B,
                                              const float* __restrict__ bias,
                                              float* __restrict__ Cout,
                                              int M, int K, int NC) {
    __shared__ float As[32][64];   // [k][row]
    __shared__ float Bs[32][64];   // [k][col]
    int tid = threadIdx.x;
    int row0 = blockIdx.x * 64;
    int col0 = blockIdx.y * 64;
    int tx = tid & 15, ty = tid >> 4;

    float acc[4][4];
#pragma unroll
    for (int i = 0; i < 4; ++i)
#pragma unroll
        for (int j = 0; j < 4; ++j) acc[i][j] = 0.f;

    int ar = tid >> 2;            // 0..63  (A tile row)
    int ak = (tid & 3) * 8;       // 0,8,16,24 (A tile k base)
    int bk = tid >> 3;            // 0..31  (B tile k)
    int bc = (tid & 7) * 8;       // 0..56  (B tile col base)

    for (int k0 = 0; k0 < K; k0 += 32) {
        // stage A (transposed into [k][row])
        float4 a0, a1;
        if (row0 + ar < M) {
            const float* ap = &A[(size_t)(row0 + ar) * K + k0 + ak];
            a0 = *reinterpret_cast<const float4*>(ap);
            a1 = *reinterpret_cast<const float4*>(ap + 4);
        } else {
            a0 = make_float4(0.f, 0.f, 0.f, 0.f);
            a1 = a0;
        }
        As[ak + 0][ar] = a0.x; As[ak + 1][ar] = a0.y;
        As[ak + 2][ar] = a0.z; As[ak + 3][ar] = a0.w;
        As[ak + 4][ar] = a1.x; As[ak + 5][ar] = a1.y;
        As[ak + 6][ar] = a1.z; As[ak + 7][ar] = a1.w;
        // stage B
        {
            const float* bp = &B[(size_t)(k0 + bk) * NC + col0 + bc];
            float4 b0 = *reinterpret_cast<const float4*>(bp);
            float4 b1 = *reinterpret_cast<const float4*>(bp + 4);
            *reinterpret_cast<float4*>(&Bs[bk][bc]) = b0;
            *reinterpret_cast<float4*>(&Bs[bk][bc + 4]) = b1;
        }
        __syncthreads();
#pragma unroll
        for (int k = 0; k < 32; ++k) {
            float4 av = *reinterpret_cast<const float4*>(&As[k][ty * 4]);
            float4 bv = *reinterpret_cast<const float4*>(&Bs[k][tx * 4]);
            float a[4] = {av.x, av.y, av.z, av.w};
            float b[4] = {bv.x, bv.y, bv.z, bv.w};
#pragma unroll
            for (int i = 0; i < 4; ++i)
#pragma unroll
                for (int j = 0; j < 4; ++j) acc[i][j] += a[i] * b[j];
        }
        __syncthreads();
    }

#pragma unroll
    for (int i = 0; i < 4; ++i) {
        int row = row0 + ty * 4 + i;
        if (row < M) {
            float4 v;
            v.x = acc[i][0]; v.y = acc[i][1]; v.z = acc[i][2]; v.w = acc[i][3];
            if (bias) {
                int c = col0 + tx * 4;
                v.x += bias[c]; v.y += bias[c + 1]; v.z += bias[c + 2]; v.w += bias[c + 3];
            }
            *reinterpret_cast<float4*>(&Cout[(size_t)row * NC + col0 + tx * 4]) = v;
        }
    }
}

// ---------------- per-node attention scores ----------------
// s_src[n][h] = sum_c h[n,h,c]*a_src[h,c] ; likewise s_dst. One wave per node.

__global__ __launch_bounds__(256) void k_scores(const float* __restrict__ h,
                                                const float* __restrict__ a_src,
                                                const float* __restrict__ a_dst,
                                                float* __restrict__ ssrc,
                                                float* __restrict__ sdst) {
    int wave = threadIdx.x >> 6, lane = threadIdx.x & 63;
    int n = blockIdx.x * 4 + wave;
    if (n >= NN) return;
#pragma unroll
    for (int hd = 0; hd < NH; ++hd) {
        float v = h[(size_t)n * HC + hd * 64 + lane];
        float p1 = v * a_src[hd * 64 + lane];
        float p2 = v * a_dst[hd * 64 + lane];
#pragma unroll
        for (int off = 32; off > 0; off >>= 1) {
            p1 += __shfl_xor(p1, off);
            p2 += __shfl_xor(p2, off);
        }
        if (lane == 0) {
            ssrc[n * NH + hd] = p1;
            sdst[n * NH + hd] = p2;
        }
    }
}

// ---------------- edge softmax + aggregation (dst-major, CSR) ----------------
// One block (256 threads) per destination node. Thread t owns output channel t.

__global__ __launch_bounds__(256) void k_agg(const float* __restrict__ h,
                                             const float* __restrict__ ssrc,
                                             const float* __restrict__ sdst,
                                             const int* __restrict__ rowptr,
                                             const int* __restrict__ col,
                                             const float* __restrict__ bias,
                                             float* __restrict__ out,
                                             int do_elu) {
    int n = blockIdx.x;
    int tid = threadIdx.x;
    int start = rowptr[n], end = rowptr[n + 1];
    int deg = end - start;

    __shared__ float m_s[NH], den_s[NH];
    __shared__ float alpha_s[128][NH];
    __shared__ int col_s[128];

    // phase 1: online softmax stats over incoming edges (wave 0)
    if (tid < 64) {
        float mx[NH], sm[NH], sd[NH];
#pragma unroll
        for (int hd = 0; hd < NH; ++hd) {
            mx[hd] = -1e30f; sm[hd] = 0.f; sd[hd] = sdst[n * NH + hd];
        }
        for (int i = tid; i < deg; i += 64) {
            int s = col[start + i];
#pragma unroll
            for (int hd = 0; hd < NH; ++hd) {
                float e = ssrc[s * NH + hd] + sd[hd];
                e = (e > 0.f) ? e : NEG_SLOPE * e;
                float nm = fmaxf(mx[hd], e);
                sm[hd] = sm[hd] * __expf(mx[hd] - nm) + __expf(e - nm);
                mx[hd] = nm;
            }
        }
#pragma unroll
        for (int off = 32; off > 0; off >>= 1) {
#pragma unroll
            for (int hd = 0; hd < NH; ++hd) {
                float omx = __shfl_xor(mx[hd], off);
                float osm = __shfl_xor(sm[hd], off);
                float nm = fmaxf(mx[hd], omx);
                sm[hd] = sm[hd] * __expf(mx[hd] - nm) + osm * __expf(omx - nm);
                mx[hd] = nm;
            }
        }
        if (tid == 0) {
#pragma unroll
            for (int hd = 0; hd < NH; ++hd) { m_s[hd] = mx[hd]; den_s[hd] = sm[hd]; }
        }
    }
    __syncthreads();

    float accv = 0.f;
    int hd = tid >> 6;

    for (int c0 = 0; c0 < deg; c0 += 128) {
        int cnt = min(128, deg - c0);
        if (tid < cnt) {
            int s = col[start + c0 + tid];
            col_s[tid] = s;
#pragma unroll
            for (int h2 = 0; h2 < NH; ++h2) {
                float e = ssrc[s * NH + h2] + sdst[n * NH + h2];
                e = (e > 0.f) ? e : NEG_SLOPE * e;
                alpha_s[tid][h2] = __expf(e - m_s[h2]) / den_s[h2];
            }
        }
        __syncthreads();
        for (int i = 0; i < cnt; ++i) {
            accv += h[(size_t)col_s[i] * HC + tid] * alpha_s[i][hd];
        }
        __syncthreads();
    }

    float r = accv + bias[tid];
    if (do_elu) r = (r > 0.f) ? r : expm1f(r);
    out[(size_t)n * HC + tid] = r;
}

// ---------------- launch ----------------

extern "C" void kernel_launch(void* const* d_in, const int* in_sizes, int n_in,
                              void* d_out, int out_size, void* d_ws, size_t ws_size,
                              hipStream_t stream) {
    const float* x      = (const float*)d_in[0];   // [2, NN, FIN]
    const int*   ei     = (const int*)d_in[1];     // [2, NE]
    const float* W1     = (const float*)d_in[2];   // [FIN, HC]
    const float* a_src1 = (const float*)d_in[3];   // [NH, CH]
    const float* a_dst1 = (const float*)d_in[4];
    const float* b1     = (const float*)d_in[5];   // [HC]
    const float* W2     = (const float*)d_in[6];   // [HC, HC]
    const float* a_src2 = (const float*)d_in[7];
    const float* a_dst2 = (const float*)d_in[8];
    const float* b2     = (const float*)d_in[9];
    const float* Wf     = (const float*)d_in[10];  // [HC, CH]
    const float* bf     = (const float*)d_in[11];  // [CH]
    float* out = (float*)d_out;                    // [2, NN, CH]

    float* ws = (float*)d_ws;
    float* Hbuf = ws;                       // NN*HC
    float* Obuf = Hbuf + (size_t)NN * HC;   // NN*HC
    float* Ssrc = Obuf + (size_t)NN * HC;   // NN*NH
    float* Sdst = Ssrc + (size_t)NN * NH;   // NN*NH
    int* counts = (int*)(Sdst + (size_t)NN * NH);
    int* rowptr = counts + NN;              // NN+1
    int* cursor = rowptr + (NN + 1);
    int* colidx = cursor + NN;              // ETOT

    // ---- CSR build (edge structure shared across batches/layers) ----
    k_zero_i32<<<(NN + 255) / 256, 256, 0, stream>>>(counts, NN);
    k_hist<<<(ETOT + 255) / 256, 256, 0, stream>>>(ei, counts);
    k_scan<<<1, 1024, 0, stream>>>(counts, rowptr);
    k_copy_i32<<<(NN + 255) / 256, 256, 0, stream>>>(rowptr, cursor, NN);
    k_scatter<<<(ETOT + 255) / 256, 256, 0, stream>>>(ei, cursor, colidx);

    const int gM = (NN + 63) / 64;  // 313
    for (int b = 0; b < 2; ++b) {
        const float* xb = x + (size_t)b * NN * FIN;
        float* outb = out + (size_t)b * NN * CH;
        // layer 1
        k_gemm<<<dim3(gM, HC / 64), 256, 0, stream>>>(xb, W1, nullptr, Hbuf, NN, FIN, HC);
        k_scores<<<NN / 4, 256, 0, stream>>>(Hbuf, a_src1, a_dst1, Ssrc, Sdst);
        k_agg<<<NN, 256, 0, stream>>>(Hbuf, Ssrc, Sdst, rowptr, colidx, b1, Obuf, 1);
        // layer 2
        k_gemm<<<dim3(gM, HC / 64), 256, 0, stream>>>(Obuf, W2, nullptr, Hbuf, NN, HC, HC);
        k_scores<<<NN / 4, 256, 0, stream>>>(Hbuf, a_src2, a_dst2, Ssrc, Sdst);
        k_agg<<<NN, 256, 0, stream>>>(Hbuf, Ssrc, Sdst, rowptr, colidx, b2, Obuf, 0);
        // final projection
        k_gemm<<<dim3(gM, CH / 64), 256, 0, stream>>>(Obuf, Wf, bf, outb, NN, HC, CH);
    }
}

// Round 2
// 458.849 us; speedup vs baseline: 1.1831x; 1.1831x over previous
//
#include <hip/hip_runtime.h>
#include <math.h>

#define NN 20000          // nodes per graph
#define NE 320000         // edges (before self loops)
#define ETOT (NE + NN)    // edges + self loops
#define NH 4              // heads
#define CH 64             // channels per head
#define HC 256            // NH*CH
#define FIN 128           // layer-1 input features
#define NEG_SLOPE 0.2f

typedef unsigned short ushort_t;
typedef unsigned int uint_t;

__device__ __forceinline__ ushort_t f2bf(float f) {
    uint_t u = __float_as_uint(f);
    u = (u + 0x7fff + ((u >> 16) & 1)) >> 16;   // RNE
    return (ushort_t)u;
}

// ---------------- CSR build ----------------

__global__ void k_zero_i32(int* __restrict__ p, int n) {
    int i = blockIdx.x * blockDim.x + threadIdx.x;
    if (i < n) p[i] = 0;
}

__global__ void k_hist(const int* __restrict__ ei, int* __restrict__ counts) {
    int e = blockIdx.x * blockDim.x + threadIdx.x;
    if (e >= ETOT) return;
    int d = (e < NE) ? ei[NE + e] : (e - NE);
    atomicAdd(&counts[d], 1);
}

__global__ void k_scan(const int* __restrict__ counts, int* __restrict__ rowptr) {
    __shared__ int part[1024];
    int tid = threadIdx.x;
    const int n = NN;
    int chunk = (n + 1023) / 1024;
    int b = tid * chunk;
    int e = min(b + chunk, n);
    int s = 0;
    for (int i = b; i < e; ++i) s += counts[i];
    part[tid] = s;
    __syncthreads();
    for (int off = 1; off < 1024; off <<= 1) {
        int v = (tid >= off) ? part[tid - off] : 0;
        __syncthreads();
        part[tid] += v;
        __syncthreads();
    }
    int ex = (tid > 0) ? part[tid - 1] : 0;
    for (int i = b; i < e; ++i) { rowptr[i] = ex; ex += counts[i]; }
    if (tid == 1023) rowptr[n] = part[1023];
}

__global__ void k_copy_i32(const int* __restrict__ s, int* __restrict__ d, int n) {
    int i = blockIdx.x * blockDim.x + threadIdx.x;
    if (i < n) d[i] = s[i];
}

__global__ void k_scatter(const int* __restrict__ ei, int* __restrict__ cursor,
                          int* __restrict__ col) {
    int e = blockIdx.x * blockDim.x + threadIdx.x;
    if (e >= ETOT) return;
    int s, d;
    if (e < NE) { s = ei[e]; d = ei[NE + e]; }
    else        { s = e - NE; d = s; }
    int pos = atomicAdd(&cursor[d], 1);
    col[pos] = s;
}

// ---------------- fp32 tiled GEMM: C[M,NC] = A[M,K] @ B[K,NC] (+bias) ----------------
// 64x64 tile, 256 threads, 4x4 micro-tile. Optionally dual-stores bf16 copy.

__global__ __launch_bounds__(256) void k_gemm(const float* __restrict__ A,
                                              const float* __restrict__ B,
                                              const float* __restrict__ bias,
                                              float* __restrict__ Cout,
                                              ushort_t* __restrict__ Cb16,
                                              int M, int K, int NC) {
    __shared__ float As[32][64];   // [k][row]
    __shared__ float Bs[32][64];   // [k][col]
    int tid = threadIdx.x;
    int row0 = blockIdx.x * 64;
    int col0 = blockIdx.y * 64;
    int tx = tid & 15, ty = tid >> 4;

    float acc[4][4];
#pragma unroll
    for (int i = 0; i < 4; ++i)
#pragma unroll
        for (int j = 0; j < 4; ++j) acc[i][j] = 0.f;

    int ar = tid >> 2;            // 0..63  (A tile row)
    int ak = (tid & 3) * 8;       // 0,8,16,24 (A tile k base)
    int bk = tid >> 3;            // 0..31  (B tile k)
    int bc = (tid & 7) * 8;       // 0..56  (B tile col base)

    for (int k0 = 0; k0 < K; k0 += 32) {
        float4 a0, a1;
        if (row0 + ar < M) {
            const float* ap = &A[(size_t)(row0 + ar) * K + k0 + ak];
            a0 = *reinterpret_cast<const float4*>(ap);
            a1 = *reinterpret_cast<const float4*>(ap + 4);
        } else {
            a0 = make_float4(0.f, 0.f, 0.f, 0.f);
            a1 = a0;
        }
        As[ak + 0][ar] = a0.x; As[ak + 1][ar] = a0.y;
        As[ak + 2][ar] = a0.z; As[ak + 3][ar] = a0.w;
        As[ak + 4][ar] = a1.x; As[ak + 5][ar] = a1.y;
        As[ak + 6][ar] = a1.z; As[ak + 7][ar] = a1.w;
        {
            const float* bp = &B[(size_t)(k0 + bk) * NC + col0 + bc];
            float4 b0 = *reinterpret_cast<const float4*>(bp);
            float4 b1 = *reinterpret_cast<const float4*>(bp + 4);
            *reinterpret_cast<float4*>(&Bs[bk][bc]) = b0;
            *reinterpret_cast<float4*>(&Bs[bk][bc + 4]) = b1;
        }
        __syncthreads();
#pragma unroll
        for (int k = 0; k < 32; ++k) {
            float4 av = *reinterpret_cast<const float4*>(&As[k][ty * 4]);
            float4 bv = *reinterpret_cast<const float4*>(&Bs[k][tx * 4]);
            float a[4] = {av.x, av.y, av.z, av.w};
            float b[4] = {bv.x, bv.y, bv.z, bv.w};
#pragma unroll
            for (int i = 0; i < 4; ++i)
#pragma unroll
                for (int j = 0; j < 4; ++j) acc[i][j] += a[i] * b[j];
        }
        __syncthreads();
    }

#pragma unroll
    for (int i = 0; i < 4; ++i) {
        int row = row0 + ty * 4 + i;
        if (row < M) {
            float4 v;
            v.x = acc[i][0]; v.y = acc[i][1]; v.z = acc[i][2]; v.w = acc[i][3];
            if (bias) {
                int c = col0 + tx * 4;
                v.x += bias[c]; v.y += bias[c + 1]; v.z += bias[c + 2]; v.w += bias[c + 3];
            }
            size_t off = (size_t)row * NC + col0 + tx * 4;
            *reinterpret_cast<float4*>(&Cout[off]) = v;
            if (Cb16) {
                ushort4 u;
                u.x = f2bf(v.x); u.y = f2bf(v.y); u.z = f2bf(v.z); u.w = f2bf(v.w);
                *reinterpret_cast<ushort4*>(&Cb16[off]) = u;
            }
        }
    }
}

// ---------------- per-node attention scores ----------------

__global__ __launch_bounds__(256) void k_scores(const float* __restrict__ h,
                                                const float* __restrict__ a_src,
                                                const float* __restrict__ a_dst,
                                                float* __restrict__ ssrc,
                                                float* __restrict__ sdst) {
    int wave = threadIdx.x >> 6, lane = threadIdx.x & 63;
    int n = blockIdx.x * 4 + wave;
    if (n >= NN) return;
#pragma unroll
    for (int hd = 0; hd < NH; ++hd) {
        float v = h[(size_t)n * HC + hd * 64 + lane];
        float p1 = v * a_src[hd * 64 + lane];
        float p2 = v * a_dst[hd * 64 + lane];
#pragma unroll
        for (int off = 32; off > 0; off >>= 1) {
            p1 += __shfl_xor(p1, off);
            p2 += __shfl_xor(p2, off);
        }
        if (lane == 0) {
            ssrc[n * NH + hd] = p1;
            sdst[n * NH + hd] = p2;
        }
    }
}

// ---------------- edge softmax + aggregation (dst-major, CSR, bf16 gather) ----------------
// One block (128 threads) per destination node. Thread t owns channels 2t, 2t+1.

__global__ __launch_bounds__(128) void k_agg(const ushort_t* __restrict__ hb,
                                             const float* __restrict__ ssrc,
                                             const float* __restrict__ sdst,
                                             const int* __restrict__ rowptr,
                                             const int* __restrict__ col,
                                             const float* __restrict__ bias,
                                             float* __restrict__ out,
                                             int do_elu) {
    int n = blockIdx.x;
    int tid = threadIdx.x;           // 0..127
    int lane = tid & 63, wave = tid >> 6;
    int start = rowptr[n], end = rowptr[n + 1];
    int deg = end - start;

    __shared__ float m_s[NH], den_s[NH];
    __shared__ float redm[2][NH], reds[2][NH];
    __shared__ float alpha_s[128][NH];
    __shared__ int col_s[128];

    // phase 1: online softmax stats over incoming edges, all 128 threads
    float mx[NH], sm[NH], sd[NH];
#pragma unroll
    for (int hd = 0; hd < NH; ++hd) {
        mx[hd] = -1e30f; sm[hd] = 0.f; sd[hd] = sdst[n * NH + hd];
    }
    for (int i = tid; i < deg; i += 128) {
        int s = col[start + i];
#pragma unroll
        for (int hd = 0; hd < NH; ++hd) {
            float e = ssrc[s * NH + hd] + sd[hd];
            e = (e > 0.f) ? e : NEG_SLOPE * e;
            float nm = fmaxf(mx[hd], e);
            sm[hd] = sm[hd] * __expf(mx[hd] - nm) + __expf(e - nm);
            mx[hd] = nm;
        }
    }
#pragma unroll
    for (int off = 32; off > 0; off >>= 1) {
#pragma unroll
        for (int hd = 0; hd < NH; ++hd) {
            float omx = __shfl_xor(mx[hd], off);
            float osm = __shfl_xor(sm[hd], off);
            float nm = fmaxf(mx[hd], omx);
            sm[hd] = sm[hd] * __expf(mx[hd] - nm) + osm * __expf(omx - nm);
            mx[hd] = nm;
        }
    }
    if (lane == 0) {
#pragma unroll
        for (int hd = 0; hd < NH; ++hd) { redm[wave][hd] = mx[hd]; reds[wave][hd] = sm[hd]; }
    }
    __syncthreads();
    if (tid == 0) {
#pragma unroll
        for (int hd = 0; hd < NH; ++hd) {
            float m0 = redm[0][hd], m1 = redm[1][hd];
            float nm = fmaxf(m0, m1);
            m_s[hd] = nm;
            den_s[hd] = reds[0][hd] * __expf(m0 - nm) + reds[1][hd] * __expf(m1 - nm);
        }
    }
    __syncthreads();

    // phase 2: gather (bf16 rows, u32 per thread = 2 channels)
    float acc0 = 0.f, acc1 = 0.f;
    int hd = tid >> 5;               // channel 2t -> head (2t)/64

    for (int c0 = 0; c0 < deg; c0 += 128) {
        int cnt = min(128, deg - c0);
        if (tid < cnt) {
            int s = col[start + c0 + tid];
            col_s[tid] = s;
#pragma unroll
            for (int h2 = 0; h2 < NH; ++h2) {
                float e = ssrc[s * NH + h2] + sdst[n * NH + h2];
                e = (e > 0.f) ? e : NEG_SLOPE * e;
                alpha_s[tid][h2] = __expf(e - m_s[h2]) / den_s[h2];
            }
        }
        __syncthreads();
        for (int i = 0; i < cnt; ++i) {
            uint_t v = *reinterpret_cast<const uint_t*>(&hb[(size_t)col_s[i] * HC + 2 * tid]);
            float lo = __uint_as_float(v << 16);
            float hi = __uint_as_float(v & 0xffff0000u);
            float a = alpha_s[i][hd];
            acc0 = fmaf(lo, a, acc0);
            acc1 = fmaf(hi, a, acc1);
        }
        __syncthreads();
    }

    float r0 = acc0 + bias[2 * tid];
    float r1 = acc1 + bias[2 * tid + 1];
    if (do_elu) {
        r0 = (r0 > 0.f) ? r0 : expm1f(r0);
        r1 = (r1 > 0.f) ? r1 : expm1f(r1);
    }
    size_t off = (size_t)n * HC + 2 * tid;
    out[off] = r0;
    out[off + 1] = r1;
}

// ---------------- launch ----------------

extern "C" void kernel_launch(void* const* d_in, const int* in_sizes, int n_in,
                              void* d_out, int out_size, void* d_ws, size_t ws_size,
                              hipStream_t stream) {
    const float* x      = (const float*)d_in[0];   // [2, NN, FIN]
    const int*   ei     = (const int*)d_in[1];     // [2, NE]
    const float* W1     = (const float*)d_in[2];   // [FIN, HC]
    const float* a_src1 = (const float*)d_in[3];   // [NH, CH]
    const float* a_dst1 = (const float*)d_in[4];
    const float* b1     = (const float*)d_in[5];   // [HC]
    const float* W2     = (const float*)d_in[6];   // [HC, HC]
    const float* a_src2 = (const float*)d_in[7];
    const float* a_dst2 = (const float*)d_in[8];
    const float* b2     = (const float*)d_in[9];
    const float* Wf     = (const float*)d_in[10];  // [HC, CH]
    const float* bf     = (const float*)d_in[11];  // [CH]
    float* out = (float*)d_out;                    // [2, NN, CH]

    float* ws = (float*)d_ws;
    float* Hbuf = ws;                              // NN*HC f32
    float* Obuf = Hbuf + (size_t)NN * HC;          // NN*HC f32
    float* Ssrc = Obuf + (size_t)NN * HC;          // NN*NH
    float* Sdst = Ssrc + (size_t)NN * NH;          // NN*NH
    ushort_t* Hb16 = (ushort_t*)(Sdst + (size_t)NN * NH);  // NN*HC bf16
    int* counts = (int*)(Hb16 + (size_t)NN * HC);
    int* rowptr = counts + NN;                     // NN+1
    int* cursor = rowptr + (NN + 1);
    int* colidx = cursor + NN;                     // ETOT

    // ---- CSR build (edge structure shared across batches/layers) ----
    k_zero_i32<<<(NN + 255) / 256, 256, 0, stream>>>(counts, NN);
    k_hist<<<(ETOT + 255) / 256, 256, 0, stream>>>(ei, counts);
    k_scan<<<1, 1024, 0, stream>>>(counts, rowptr);
    k_copy_i32<<<(NN + 255) / 256, 256, 0, stream>>>(rowptr, cursor, NN);
    k_scatter<<<(ETOT + 255) / 256, 256, 0, stream>>>(ei, cursor, colidx);

    const int gM = (NN + 63) / 64;  // 313
    for (int b = 0; b < 2; ++b) {
        const float* xb = x + (size_t)b * NN * FIN;
        float* outb = out + (size_t)b * NN * CH;
        // layer 1
        k_gemm<<<dim3(gM, HC / 64), 256, 0, stream>>>(xb, W1, nullptr, Hbuf, Hb16, NN, FIN, HC);
        k_scores<<<NN / 4, 256, 0, stream>>>(Hbuf, a_src1, a_dst1, Ssrc, Sdst);
        k_agg<<<NN, 128, 0, stream>>>(Hb16, Ssrc, Sdst, rowptr, colidx, b1, Obuf, 1);
        // layer 2
        k_gemm<<<dim3(gM, HC / 64), 256, 0, stream>>>(Obuf, W2, nullptr, Hbuf, Hb16, NN, HC, HC);
        k_scores<<<NN / 4, 256, 0, stream>>>(Hbuf, a_src2, a_dst2, Ssrc, Sdst);
        k_agg<<<NN, 128, 0, stream>>>(Hb16, Ssrc, Sdst, rowptr, colidx, b2, Obuf, 0);
        // final projection
        k_gemm<<<dim3(gM, CH / 64), 256, 0, stream>>>(Obuf, Wf, bf, outb, nullptr, NN, HC, CH);
    }
}

// Round 3
// 374.902 us; speedup vs baseline: 1.4481x; 1.2239x over previous
//
#include <hip/hip_runtime.h>
#include <math.h>

#define NN 20000          // nodes per graph
#define NE 320000         // edges (before self loops)
#define ETOT (NE + NN)    // edges + self loops
#define NH 4              // heads
#define CH 64             // channels per head
#define HC 256            // NH*CH
#define FIN 128           // layer-1 input features
#define NEG_SLOPE 0.2f

typedef unsigned short ushort_t;
typedef unsigned int uint_t;
typedef _Float16 half8 __attribute__((ext_vector_type(8)));
typedef float f32x4 __attribute__((ext_vector_type(4)));

__device__ __forceinline__ ushort_t f2h_bits(float f) {
    _Float16 h = (_Float16)f;
    union { _Float16 h; ushort_t u; } c; c.h = h;
    return c.u;
}
__device__ __forceinline__ float2 h2f2(uint_t v) {
    union { uint_t u; _Float16 h[2]; } c; c.u = v;
    return make_float2((float)c.h[0], (float)c.h[1]);
}
__device__ __forceinline__ float h2f(ushort_t v) {
    union { ushort_t u; _Float16 h; } c; c.u = v;
    return (float)c.h;
}

// ---------------- CSR build ----------------

__global__ void k_zero_i32(int* __restrict__ p, int n) {
    int i = blockIdx.x * blockDim.x + threadIdx.x;
    if (i < n) p[i] = 0;
}

__global__ void k_hist(const int* __restrict__ ei, int* __restrict__ counts) {
    int e = blockIdx.x * blockDim.x + threadIdx.x;
    if (e >= ETOT) return;
    int d = (e < NE) ? ei[NE + e] : (e - NE);
    atomicAdd(&counts[d], 1);
}

__global__ void k_scan(const int* __restrict__ counts, int* __restrict__ rowptr) {
    __shared__ int part[1024];
    int tid = threadIdx.x;
    const int n = NN;
    int chunk = (n + 1023) / 1024;
    int b = tid * chunk;
    int e = min(b + chunk, n);
    int s = 0;
    for (int i = b; i < e; ++i) s += counts[i];
    part[tid] = s;
    __syncthreads();
    for (int off = 1; off < 1024; off <<= 1) {
        int v = (tid >= off) ? part[tid - off] : 0;
        __syncthreads();
        part[tid] += v;
        __syncthreads();
    }
    int ex = (tid > 0) ? part[tid - 1] : 0;
    for (int i = b; i < e; ++i) { rowptr[i] = ex; ex += counts[i]; }
    if (tid == 1023) rowptr[n] = part[1023];
}

__global__ void k_copy_i32(const int* __restrict__ s, int* __restrict__ d, int n) {
    int i = blockIdx.x * blockDim.x + threadIdx.x;
    if (i < n) d[i] = s[i];
}

__global__ void k_scatter(const int* __restrict__ ei, int* __restrict__ cursor,
                          int* __restrict__ col) {
    int e = blockIdx.x * blockDim.x + threadIdx.x;
    if (e >= ETOT) return;
    int s, d;
    if (e < NE) { s = ei[e]; d = ei[NE + e]; }
    else        { s = e - NE; d = s; }
    int pos = atomicAdd(&cursor[d], 1);
    col[pos] = s;
}

// ---------------- precision conversion helpers ----------------

__global__ void k_f2h(const float* __restrict__ src, ushort_t* __restrict__ dst, int n) {
    int i = (blockIdx.x * blockDim.x + threadIdx.x) * 4;
    if (i >= n) return;
    float4 v = *reinterpret_cast<const float4*>(&src[i]);
    ushort4 u;
    u.x = f2h_bits(v.x); u.y = f2h_bits(v.y); u.z = f2h_bits(v.z); u.w = f2h_bits(v.w);
    *reinterpret_cast<ushort4*>(&dst[i]) = u;
}

// W [K][NC] fp32 -> Wt [NC][K] f16
__global__ void k_wt(const float* __restrict__ W, ushort_t* __restrict__ Wt, int K, int NC) {
    int i = blockIdx.x * blockDim.x + threadIdx.x;
    if (i >= K * NC) return;
    int n = i / K, k = i - n * K;
    Wt[i] = f2h_bits(W[(size_t)k * NC + n]);
}

// ---------------- f16 MFMA GEMM: C[M,NC] = A[M,K] @ Bt[NC,K]^T ----------------
// 64x64 tile, 4 waves in 2x2, each wave 32x32 via 2x2 16x16x32 fragments.
// Output: f16 only (consumed by scores + gather).

__global__ __launch_bounds__(256) void k_gemm_mfma(const ushort_t* __restrict__ A,
                                                   const ushort_t* __restrict__ Bt,
                                                   ushort_t* __restrict__ Ch,
                                                   int M, int K, int NC) {
    __shared__ ushort_t As[64][40];   // padded: 80B row stride -> 2-way (free)
    __shared__ ushort_t Bs[64][40];
    int tid = threadIdx.x;
    int wave = tid >> 6, lane = tid & 63;
    int wr = wave >> 1, wc = wave & 1;
    int row0 = blockIdx.x * 64, col0 = blockIdx.y * 64;

    f32x4 acc[2][2];
#pragma unroll
    for (int i = 0; i < 2; ++i)
#pragma unroll
        for (int j = 0; j < 2; ++j) acc[i][j] = (f32x4){0.f, 0.f, 0.f, 0.f};

    int sr = tid >> 2;            // 0..63 staging row (A) / col (B)
    int sk = (tid & 3) * 8;       // 0,8,16,24
    int l15 = lane & 15, lk = (lane >> 4) * 8;

    for (int k0 = 0; k0 < K; k0 += 32) {
        uint4 av = make_uint4(0, 0, 0, 0);
        int rowg = row0 + sr;
        if (rowg < M) av = *reinterpret_cast<const uint4*>(&A[(size_t)rowg * K + k0 + sk]);
        *reinterpret_cast<uint4*>(&As[sr][sk]) = av;
        uint4 bv = *reinterpret_cast<const uint4*>(&Bt[(size_t)(col0 + sr) * K + k0 + sk]);
        *reinterpret_cast<uint4*>(&Bs[sr][sk]) = bv;
        __syncthreads();

        half8 a0 = *reinterpret_cast<const half8*>(&As[wr * 32 + l15][lk]);
        half8 a1 = *reinterpret_cast<const half8*>(&As[wr * 32 + 16 + l15][lk]);
        half8 b0 = *reinterpret_cast<const half8*>(&Bs[wc * 32 + l15][lk]);
        half8 b1 = *reinterpret_cast<const half8*>(&Bs[wc * 32 + 16 + l15][lk]);
        acc[0][0] = __builtin_amdgcn_mfma_f32_16x16x32_f16(a0, b0, acc[0][0], 0, 0, 0);
        acc[0][1] = __builtin_amdgcn_mfma_f32_16x16x32_f16(a0, b1, acc[0][1], 0, 0, 0);
        acc[1][0] = __builtin_amdgcn_mfma_f32_16x16x32_f16(a1, b0, acc[1][0], 0, 0, 0);
        acc[1][1] = __builtin_amdgcn_mfma_f32_16x16x32_f16(a1, b1, acc[1][1], 0, 0, 0);
        __syncthreads();
    }

#pragma unroll
    for (int fr = 0; fr < 2; ++fr)
#pragma unroll
        for (int fc = 0; fc < 2; ++fc) {
            int colc = col0 + wc * 32 + fc * 16 + l15;
#pragma unroll
            for (int j = 0; j < 4; ++j) {
                int row = row0 + wr * 32 + fr * 16 + (lane >> 4) * 4 + j;
                if (row < M) Ch[(size_t)row * NC + colc] = f2h_bits(acc[fr][fc][j]);
            }
        }
}

// ---------------- per-node attention scores (f16 h) ----------------

__global__ __launch_bounds__(256) void k_scores(const ushort_t* __restrict__ h,
                                                const float* __restrict__ a_src,
                                                const float* __restrict__ a_dst,
                                                float* __restrict__ ssrc,
                                                float* __restrict__ sdst) {
    int wave = threadIdx.x >> 6, lane = threadIdx.x & 63;
    int n = blockIdx.x * 4 + wave;
    if (n >= NN) return;
#pragma unroll
    for (int hd = 0; hd < NH; ++hd) {
        float v = h2f(h[(size_t)n * HC + hd * 64 + lane]);
        float p1 = v * a_src[hd * 64 + lane];
        float p2 = v * a_dst[hd * 64 + lane];
#pragma unroll
        for (int off = 32; off > 0; off >>= 1) {
            p1 += __shfl_xor(p1, off);
            p2 += __shfl_xor(p2, off);
        }
        if (lane == 0) {
            ssrc[n * NH + hd] = p1;
            sdst[n * NH + hd] = p2;
        }
    }
}

// ---------------- edge softmax + aggregation (dst-major, CSR, f16 gather) ----------------
// One block (128 threads) per destination node. Thread t owns channels 2t, 2t+1.
// Phase-2 gather is 4-deep software pipelined to hide load latency.

__global__ __launch_bounds__(128) void k_agg(const ushort_t* __restrict__ hb,
                                             const float* __restrict__ ssrc,
                                             const float* __restrict__ sdst,
                                             const int* __restrict__ rowptr,
                                             const int* __restrict__ col,
                                             const float* __restrict__ bias,
                                             float* __restrict__ out,
                                             ushort_t* __restrict__ outh,
                                             int do_elu) {
    int n = blockIdx.x;
    int tid = threadIdx.x;           // 0..127
    int lane = tid & 63, wave = tid >> 6;
    int start = rowptr[n], end = rowptr[n + 1];
    int deg = end - start;

    __shared__ float m_s[NH], den_s[NH];
    __shared__ float redm[2][NH], reds[2][NH];
    __shared__ float alpha_s[128][NH];
    __shared__ int col_s[128];       // element offsets (src*HC)

    // phase 1: online softmax stats, all 128 threads
    float mx[NH], sm[NH], sd[NH];
#pragma unroll
    for (int hd = 0; hd < NH; ++hd) {
        mx[hd] = -1e30f; sm[hd] = 0.f; sd[hd] = sdst[n * NH + hd];
    }
    for (int i = tid; i < deg; i += 128) {
        int s = col[start + i];
#pragma unroll
        for (int hd = 0; hd < NH; ++hd) {
            float e = ssrc[s * NH + hd] + sd[hd];
            e = (e > 0.f) ? e : NEG_SLOPE * e;
            float nm = fmaxf(mx[hd], e);
            sm[hd] = sm[hd] * __expf(mx[hd] - nm) + __expf(e - nm);
            mx[hd] = nm;
        }
    }
#pragma unroll
    for (int off = 32; off > 0; off >>= 1) {
#pragma unroll
        for (int hd = 0; hd < NH; ++hd) {
            float omx = __shfl_xor(mx[hd], off);
            float osm = __shfl_xor(sm[hd], off);
            float nm = fmaxf(mx[hd], omx);
            sm[hd] = sm[hd] * __expf(mx[hd] - nm) + osm * __expf(omx - nm);
            mx[hd] = nm;
        }
    }
    if (lane == 0) {
#pragma unroll
        for (int hd = 0; hd < NH; ++hd) { redm[wave][hd] = mx[hd]; reds[wave][hd] = sm[hd]; }
    }
    __syncthreads();
    if (tid == 0) {
#pragma unroll
        for (int hd = 0; hd < NH; ++hd) {
            float m0 = redm[0][hd], m1 = redm[1][hd];
            float nm = fmaxf(m0, m1);
            m_s[hd] = nm;
            den_s[hd] = reds[0][hd] * __expf(m0 - nm) + reds[1][hd] * __expf(m1 - nm);
        }
    }
    __syncthreads();

    // phase 2: pipelined gather (f16 rows, u32 per thread = 2 channels)
    float acc0 = 0.f, acc1 = 0.f;
    int hd = tid >> 5;
    const ushort_t* hbt = hb + 2 * tid;

    for (int c0 = 0; c0 < deg; c0 += 128) {
        int cnt = min(128, deg - c0);
        if (tid < cnt) {
            int s = col[start + c0 + tid];
            col_s[tid] = s * HC;
#pragma unroll
            for (int h2 = 0; h2 < NH; ++h2) {
                float e = ssrc[s * NH + h2] + sdst[n * NH + h2];
                e = (e > 0.f) ? e : NEG_SLOPE * e;
                alpha_s[tid][h2] = __expf(e - m_s[h2]) / den_s[h2];
            }
        }
        __syncthreads();
        int i = 0;
        for (; i + 4 <= cnt; i += 4) {
            int o0 = col_s[i], o1 = col_s[i + 1], o2 = col_s[i + 2], o3 = col_s[i + 3];
            uint_t v0 = *reinterpret_cast<const uint_t*>(hbt + o0);
            uint_t v1 = *reinterpret_cast<const uint_t*>(hbt + o1);
            uint_t v2 = *reinterpret_cast<const uint_t*>(hbt + o2);
            uint_t v3 = *reinterpret_cast<const uint_t*>(hbt + o3);
            float a0 = alpha_s[i][hd], a1 = alpha_s[i + 1][hd];
            float a2 = alpha_s[i + 2][hd], a3 = alpha_s[i + 3][hd];
            float2 f0 = h2f2(v0), f1 = h2f2(v1), f2 = h2f2(v2), f3 = h2f2(v3);
            acc0 = fmaf(f0.x, a0, acc0); acc1 = fmaf(f0.y, a0, acc1);
            acc0 = fmaf(f1.x, a1, acc0); acc1 = fmaf(f1.y, a1, acc1);
            acc0 = fmaf(f2.x, a2, acc0); acc1 = fmaf(f2.y, a2, acc1);
            acc0 = fmaf(f3.x, a3, acc0); acc1 = fmaf(f3.y, a3, acc1);
        }
        for (; i < cnt; ++i) {
            uint_t v = *reinterpret_cast<const uint_t*>(hbt + col_s[i]);
            float a = alpha_s[i][hd];
            float2 f = h2f2(v);
            acc0 = fmaf(f.x, a, acc0); acc1 = fmaf(f.y, a, acc1);
        }
        __syncthreads();
    }

    float r0 = acc0 + bias[2 * tid];
    float r1 = acc1 + bias[2 * tid + 1];
    if (do_elu) {
        r0 = (r0 > 0.f) ? r0 : expm1f(r0);
        r1 = (r1 > 0.f) ? r1 : expm1f(r1);
    }
    size_t off = (size_t)n * HC + 2 * tid;
    out[off] = r0;
    out[off + 1] = r1;
    outh[off] = f2h_bits(r0);
    outh[off + 1] = f2h_bits(r1);
}

// ---------------- fp32 tiled GEMM (final projection) ----------------

__global__ __launch_bounds__(256) void k_gemm(const float* __restrict__ A,
                                              const float* __restrict__ B,
                                              const float* __restrict__ bias,
                                              float* __restrict__ Cout,
                                              int M, int K, int NC) {
    __shared__ float As[32][64];
    __shared__ float Bs[32][64];
    int tid = threadIdx.x;
    int row0 = blockIdx.x * 64;
    int col0 = blockIdx.y * 64;
    int tx = tid & 15, ty = tid >> 4;

    float acc[4][4];
#pragma unroll
    for (int i = 0; i < 4; ++i)
#pragma unroll
        for (int j = 0; j < 4; ++j) acc[i][j] = 0.f;

    int ar = tid >> 2;
    int ak = (tid & 3) * 8;
    int bk = tid >> 3;
    int bc = (tid & 7) * 8;

    for (int k0 = 0; k0 < K; k0 += 32) {
        float4 a0, a1;
        if (row0 + ar < M) {
            const float* ap = &A[(size_t)(row0 + ar) * K + k0 + ak];
            a0 = *reinterpret_cast<const float4*>(ap);
            a1 = *reinterpret_cast<const float4*>(ap + 4);
        } else {
            a0 = make_float4(0.f, 0.f, 0.f, 0.f);
            a1 = a0;
        }
        As[ak + 0][ar] = a0.x; As[ak + 1][ar] = a0.y;
        As[ak + 2][ar] = a0.z; As[ak + 3][ar] = a0.w;
        As[ak + 4][ar] = a1.x; As[ak + 5][ar] = a1.y;
        As[ak + 6][ar] = a1.z; As[ak + 7][ar] = a1.w;
        {
            const float* bp = &B[(size_t)(k0 + bk) * NC + col0 + bc];
            float4 b0 = *reinterpret_cast<const float4*>(bp);
            float4 b1 = *reinterpret_cast<const float4*>(bp + 4);
            *reinterpret_cast<float4*>(&Bs[bk][bc]) = b0;
            *reinterpret_cast<float4*>(&Bs[bk][bc + 4]) = b1;
        }
        __syncthreads();
#pragma unroll
        for (int k = 0; k < 32; ++k) {
            float4 av = *reinterpret_cast<const float4*>(&As[k][ty * 4]);
            float4 bv = *reinterpret_cast<const float4*>(&Bs[k][tx * 4]);
            float a[4] = {av.x, av.y, av.z, av.w};
            float b[4] = {bv.x, bv.y, bv.z, bv.w};
#pragma unroll
            for (int i = 0; i < 4; ++i)
#pragma unroll
                for (int j = 0; j < 4; ++j) acc[i][j] += a[i] * b[j];
        }
        __syncthreads();
    }

#pragma unroll
    for (int i = 0; i < 4; ++i) {
        int row = row0 + ty * 4 + i;
        if (row < M) {
            float4 v;
            v.x = acc[i][0]; v.y = acc[i][1]; v.z = acc[i][2]; v.w = acc[i][3];
            if (bias) {
                int c = col0 + tx * 4;
                v.x += bias[c]; v.y += bias[c + 1]; v.z += bias[c + 2]; v.w += bias[c + 3];
            }
            *reinterpret_cast<float4*>(&Cout[(size_t)row * NC + col0 + tx * 4]) = v;
        }
    }
}

// ---------------- launch ----------------

extern "C" void kernel_launch(void* const* d_in, const int* in_sizes, int n_in,
                              void* d_out, int out_size, void* d_ws, size_t ws_size,
                              hipStream_t stream) {
    const float* x      = (const float*)d_in[0];   // [2, NN, FIN]
    const int*   ei     = (const int*)d_in[1];     // [2, NE]
    const float* W1     = (const float*)d_in[2];   // [FIN, HC]
    const float* a_src1 = (const float*)d_in[3];
    const float* a_dst1 = (const float*)d_in[4];
    const float* b1     = (const float*)d_in[5];
    const float* W2     = (const float*)d_in[6];   // [HC, HC]
    const float* a_src2 = (const float*)d_in[7];
    const float* a_dst2 = (const float*)d_in[8];
    const float* b2     = (const float*)d_in[9];
    const float* Wf     = (const float*)d_in[10];  // [HC, CH]
    const float* bf     = (const float*)d_in[11];
    float* out = (float*)d_out;                    // [2, NN, CH]

    float* ws = (float*)d_ws;
    float* Obuf = ws;                              // NN*HC f32 (agg out)
    float* Ssrc = Obuf + (size_t)NN * HC;          // NN*NH
    float* Sdst = Ssrc + (size_t)NN * NH;          // NN*NH
    ushort_t* Hb16 = (ushort_t*)(Sdst + (size_t)NN * NH);  // NN*HC f16 (gemm out)
    ushort_t* Ob16 = Hb16 + (size_t)NN * HC;       // NN*HC f16 (agg out)
    ushort_t* Xb16 = Ob16 + (size_t)NN * HC;       // NN*FIN f16
    ushort_t* Wt1  = Xb16 + (size_t)NN * FIN;      // HC*FIN
    ushort_t* Wt2  = Wt1 + (size_t)HC * FIN;       // HC*HC
    int* counts = (int*)(Wt2 + (size_t)HC * HC);
    int* rowptr = counts + NN;
    int* cursor = rowptr + (NN + 1);
    int* colidx = cursor + NN;                     // ETOT

    // ---- CSR build ----
    k_zero_i32<<<(NN + 255) / 256, 256, 0, stream>>>(counts, NN);
    k_hist<<<(ETOT + 255) / 256, 256, 0, stream>>>(ei, counts);
    k_scan<<<1, 1024, 0, stream>>>(counts, rowptr);
    k_copy_i32<<<(NN + 255) / 256, 256, 0, stream>>>(rowptr, cursor, NN);
    k_scatter<<<(ETOT + 255) / 256, 256, 0, stream>>>(ei, cursor, colidx);

    // ---- weight transpose + convert (once) ----
    k_wt<<<(FIN * HC + 255) / 256, 256, 0, stream>>>(W1, Wt1, FIN, HC);
    k_wt<<<(HC * HC + 255) / 256, 256, 0, stream>>>(W2, Wt2, HC, HC);

    const int gM = (NN + 63) / 64;  // 313
    for (int b = 0; b < 2; ++b) {
        const float* xb = x + (size_t)b * NN * FIN;
        float* outb = out + (size_t)b * NN * CH;
        // layer 1
        k_f2h<<<(NN * FIN / 4 + 255) / 256, 256, 0, stream>>>(xb, Xb16, NN * FIN);
        k_gemm_mfma<<<dim3(gM, HC / 64), 256, 0, stream>>>(Xb16, Wt1, Hb16, NN, FIN, HC);
        k_scores<<<NN / 4, 256, 0, stream>>>(Hb16, a_src1, a_dst1, Ssrc, Sdst);
        k_agg<<<NN, 128, 0, stream>>>(Hb16, Ssrc, Sdst, rowptr, colidx, b1, Obuf, Ob16, 1);
        // layer 2
        k_gemm_mfma<<<dim3(gM, HC / 64), 256, 0, stream>>>(Ob16, Wt2, Hb16, NN, HC, HC);
        k_scores<<<NN / 4, 256, 0, stream>>>(Hb16, a_src2, a_dst2, Ssrc, Sdst);
        k_agg<<<NN, 128, 0, stream>>>(Hb16, Ssrc, Sdst, rowptr, colidx, b2, Obuf, Ob16, 0);
        // final projection (fp32)
        k_gemm<<<dim3(gM, CH / 64), 256, 0, stream>>>(Obuf, Wf, bf, outb, NN, HC, CH);
    }
}

// Round 4
// 289.225 us; speedup vs baseline: 1.8770x; 1.2962x over previous
//
#include <hip/hip_runtime.h>
#include <math.h>

#define NN 20000          // nodes per graph
#define NE 320000         // edges (before self loops)
#define ETOT (NE + NN)    // edges + self loops
#define NH 4              // heads
#define CH 64             // channels per head
#define HC 256            // NH*CH
#define FIN 128           // layer-1 input features
#define NEG_SLOPE 0.2f
#define CAP 96            // edges per softmax chunk (deg>CAP handled flash-style)

typedef unsigned short ushort_t;
typedef unsigned int uint_t;
typedef _Float16 half8 __attribute__((ext_vector_type(8)));
typedef float f32x4 __attribute__((ext_vector_type(4)));

__device__ __forceinline__ ushort_t f2h_bits(float f) {
    union { _Float16 h; ushort_t u; } c; c.h = (_Float16)f;
    return c.u;
}
__device__ __forceinline__ float h2f(ushort_t v) {
    union { ushort_t u; _Float16 h; } c; c.u = v;
    return (float)c.h;
}

// ---------------- CSR build ----------------

__global__ void k_zero_i32(int* __restrict__ p, int n) {
    int i = blockIdx.x * blockDim.x + threadIdx.x;
    if (i < n) p[i] = 0;
}

__global__ void k_hist(const int* __restrict__ ei, int* __restrict__ counts) {
    int e = blockIdx.x * blockDim.x + threadIdx.x;
    if (e >= ETOT) return;
    int d = (e < NE) ? ei[NE + e] : (e - NE);
    atomicAdd(&counts[d], 1);
}

__global__ void k_scan(const int* __restrict__ counts, int* __restrict__ rowptr) {
    __shared__ int part[1024];
    int tid = threadIdx.x;
    const int n = NN;
    int chunk = (n + 1023) / 1024;
    int b = tid * chunk;
    int e = min(b + chunk, n);
    int s = 0;
    for (int i = b; i < e; ++i) s += counts[i];
    part[tid] = s;
    __syncthreads();
    for (int off = 1; off < 1024; off <<= 1) {
        int v = (tid >= off) ? part[tid - off] : 0;
        __syncthreads();
        part[tid] += v;
        __syncthreads();
    }
    int ex = (tid > 0) ? part[tid - 1] : 0;
    for (int i = b; i < e; ++i) { rowptr[i] = ex; ex += counts[i]; }
    if (tid == 1023) rowptr[n] = part[1023];
}

__global__ void k_copy_i32(const int* __restrict__ s, int* __restrict__ d, int n) {
    int i = blockIdx.x * blockDim.x + threadIdx.x;
    if (i < n) d[i] = s[i];
}

__global__ void k_scatter(const int* __restrict__ ei, int* __restrict__ cursor,
                          int* __restrict__ col) {
    int e = blockIdx.x * blockDim.x + threadIdx.x;
    if (e >= ETOT) return;
    int s, d;
    if (e < NE) { s = ei[e]; d = ei[NE + e]; }
    else        { s = e - NE; d = s; }
    int pos = atomicAdd(&cursor[d], 1);
    col[pos] = s;
}

// ---------------- precision conversion helpers ----------------

__global__ void k_f2h(const float* __restrict__ src, ushort_t* __restrict__ dst, int n) {
    int i = (blockIdx.x * blockDim.x + threadIdx.x) * 4;
    if (i >= n) return;
    float4 v = *reinterpret_cast<const float4*>(&src[i]);
    ushort4 u;
    u.x = f2h_bits(v.x); u.y = f2h_bits(v.y); u.z = f2h_bits(v.z); u.w = f2h_bits(v.w);
    *reinterpret_cast<ushort4*>(&dst[i]) = u;
}

// W [K][NC] fp32 -> Wt [NC][K] f16
__global__ void k_wt(const float* __restrict__ W, ushort_t* __restrict__ Wt, int K, int NC) {
    int i = blockIdx.x * blockDim.x + threadIdx.x;
    if (i >= K * NC) return;
    int n = i / K, k = i - n * K;
    Wt[i] = f2h_bits(W[(size_t)k * NC + n]);
}

// ---------------- f16 MFMA GEMM: C[M,NC] = A[M,K] @ Bt[NC,K]^T ----------------
// 64x64 tile, 4 waves in 2x2, each wave 32x32 via 2x2 16x16x32 fragments.
// Output: f16 (Ch) or f32+bias (Cf).

__global__ __launch_bounds__(256) void k_gemm_mfma(const ushort_t* __restrict__ A,
                                                   const ushort_t* __restrict__ Bt,
                                                   ushort_t* __restrict__ Ch,
                                                   float* __restrict__ Cf,
                                                   const float* __restrict__ bias,
                                                   int M, int K, int NC) {
    __shared__ ushort_t As[64][40];   // padded: 80B row stride -> 2-way (free)
    __shared__ ushort_t Bs[64][40];
    int tid = threadIdx.x;
    int wave = tid >> 6, lane = tid & 63;
    int wr = wave >> 1, wc = wave & 1;
    int row0 = blockIdx.x * 64, col0 = blockIdx.y * 64;

    f32x4 acc[2][2];
#pragma unroll
    for (int i = 0; i < 2; ++i)
#pragma unroll
        for (int j = 0; j < 2; ++j) acc[i][j] = (f32x4){0.f, 0.f, 0.f, 0.f};

    int sr = tid >> 2;
    int sk = (tid & 3) * 8;
    int l15 = lane & 15, lk = (lane >> 4) * 8;

    for (int k0 = 0; k0 < K; k0 += 32) {
        uint4 av = make_uint4(0, 0, 0, 0);
        int rowg = row0 + sr;
        if (rowg < M) av = *reinterpret_cast<const uint4*>(&A[(size_t)rowg * K + k0 + sk]);
        *reinterpret_cast<uint4*>(&As[sr][sk]) = av;
        uint4 bv = *reinterpret_cast<const uint4*>(&Bt[(size_t)(col0 + sr) * K + k0 + sk]);
        *reinterpret_cast<uint4*>(&Bs[sr][sk]) = bv;
        __syncthreads();

        half8 a0 = *reinterpret_cast<const half8*>(&As[wr * 32 + l15][lk]);
        half8 a1 = *reinterpret_cast<const half8*>(&As[wr * 32 + 16 + l15][lk]);
        half8 b0 = *reinterpret_cast<const half8*>(&Bs[wc * 32 + l15][lk]);
        half8 b1 = *reinterpret_cast<const half8*>(&Bs[wc * 32 + 16 + l15][lk]);
        acc[0][0] = __builtin_amdgcn_mfma_f32_16x16x32_f16(a0, b0, acc[0][0], 0, 0, 0);
        acc[0][1] = __builtin_amdgcn_mfma_f32_16x16x32_f16(a0, b1, acc[0][1], 0, 0, 0);
        acc[1][0] = __builtin_amdgcn_mfma_f32_16x16x32_f16(a1, b0, acc[1][0], 0, 0, 0);
        acc[1][1] = __builtin_amdgcn_mfma_f32_16x16x32_f16(a1, b1, acc[1][1], 0, 0, 0);
        __syncthreads();
    }

#pragma unroll
    for (int fr = 0; fr < 2; ++fr)
#pragma unroll
        for (int fc = 0; fc < 2; ++fc) {
            int colc = col0 + wc * 32 + fc * 16 + l15;
#pragma unroll
            for (int j = 0; j < 4; ++j) {
                int row = row0 + wr * 32 + fr * 16 + (lane >> 4) * 4 + j;
                if (row < M) {
                    if (Cf) Cf[(size_t)row * NC + colc] = acc[fr][fc][j] + bias[colc];
                    else    Ch[(size_t)row * NC + colc] = f2h_bits(acc[fr][fc][j]);
                }
            }
        }
}

// ---------------- per-node attention scores (f16 h, batch-fused M=2*NN) ----------------

__global__ __launch_bounds__(256) void k_scores(const ushort_t* __restrict__ h,
                                                const float* __restrict__ a_src,
                                                const float* __restrict__ a_dst,
                                                float* __restrict__ ssrc,
                                                float* __restrict__ sdst) {
    int wave = threadIdx.x >> 6, lane = threadIdx.x & 63;
    int n = blockIdx.x * 4 + wave;
    if (n >= 2 * NN) return;
#pragma unroll
    for (int hd = 0; hd < NH; ++hd) {
        float v = h2f(h[(size_t)n * HC + hd * 64 + lane]);
        float p1 = v * a_src[hd * 64 + lane];
        float p2 = v * a_dst[hd * 64 + lane];
#pragma unroll
        for (int off = 32; off > 0; off >>= 1) {
            p1 += __shfl_xor(p1, off);
            p2 += __shfl_xor(p2, off);
        }
        if (lane == 0) {
            ssrc[n * NH + hd] = p1;
            sdst[n * NH + hd] = p2;
        }
    }
}

// ---------------- edge softmax + aggregation, batch-fused, one wave per node ----------------
// Wave handles graph-node n for BOTH batches. Lane l owns channels [4l,4l+4).
// Flash-style chunked softmax: e -> LDS (transposed), plain-max reduce, exp-ize,
// sum reduce, gather with unnormalized weights, divide at end. No barriers.

__global__ __launch_bounds__(256) void k_agg(const ushort_t* __restrict__ hb,   // [2*NN][HC] f16
                                             const float* __restrict__ ssrc,    // [2*NN][NH]
                                             const float* __restrict__ sdst,
                                             const int* __restrict__ rowptr,
                                             const int* __restrict__ col,
                                             const float* __restrict__ bias,
                                             ushort_t* __restrict__ outh,       // [2*NN][HC] f16
                                             int do_elu) {
    __shared__ int cols_lds[4][CAP];
    __shared__ float e_lds[4][8 * CAP];    // [combo][edge], conflict-free
    int wave = threadIdx.x >> 6, lane = threadIdx.x & 63;
    int n = blockIdx.x * 4 + wave;
    if (n >= NN) return;
    int* colw = cols_lds[wave];
    float* ew = e_lds[wave];
    int start = rowptr[n];
    int deg = rowptr[n + 1] - start;
    int hsel = lane >> 4;

    float sd[8];
    {
        float4 s0 = *reinterpret_cast<const float4*>(&sdst[(size_t)n * NH]);
        float4 s1 = *reinterpret_cast<const float4*>(&sdst[((size_t)NN + n) * NH]);
        sd[0] = s0.x; sd[1] = s0.y; sd[2] = s0.z; sd[3] = s0.w;
        sd[4] = s1.x; sd[5] = s1.y; sd[6] = s1.z; sd[7] = s1.w;
    }

    float mx[8], den[8], acc[8];
#pragma unroll
    for (int c = 0; c < 8; ++c) { mx[c] = -1e30f; den[c] = 0.f; acc[c] = 0.f; }

    const ushort_t* hb0 = hb + 4 * lane;
    const ushort_t* hb1 = hb + (size_t)NN * HC + 4 * lane;

    for (int c0 = 0; c0 < deg; c0 += CAP) {
        int cnt = min(CAP, deg - c0);

        // phase A: e values into LDS + per-lane chunk max
        float cm[8];
#pragma unroll
        for (int c = 0; c < 8; ++c) cm[c] = -1e30f;
        for (int i = lane; i < cnt; i += 64) {
            int s = col[start + c0 + i];
            colw[i] = s * HC;
            float4 p0 = *reinterpret_cast<const float4*>(&ssrc[(size_t)s * NH]);
            float4 p1 = *reinterpret_cast<const float4*>(&ssrc[((size_t)NN + s) * NH]);
            float e[8];
            e[0] = p0.x + sd[0]; e[1] = p0.y + sd[1]; e[2] = p0.z + sd[2]; e[3] = p0.w + sd[3];
            e[4] = p1.x + sd[4]; e[5] = p1.y + sd[5]; e[6] = p1.z + sd[6]; e[7] = p1.w + sd[7];
#pragma unroll
            for (int c = 0; c < 8; ++c) {
                e[c] = fmaxf(e[c], NEG_SLOPE * e[c]);   // leaky relu (slope<1)
                cm[c] = fmaxf(cm[c], e[c]);
                ew[c * CAP + i] = e[c];
            }
        }
#pragma unroll
        for (int off = 32; off > 0; off >>= 1)
#pragma unroll
            for (int c = 0; c < 8; ++c) cm[c] = fmaxf(cm[c], __shfl_xor(cm[c], off));

        // merge running max; rescale acc & den
        float scl[8];
#pragma unroll
        for (int c = 0; c < 8; ++c) {
            float nm = fmaxf(mx[c], cm[c]);
            scl[c] = __expf(mx[c] - nm);
            den[c] *= scl[c];
            mx[c] = nm;
        }
        float sA = scl[hsel], sB = scl[4 + hsel];
#pragma unroll
        for (int j = 0; j < 4; ++j) { acc[j] *= sA; acc[4 + j] *= sB; }

        // phase B: exp-ize in LDS + denominator partial sums
        float pd[8];
#pragma unroll
        for (int c = 0; c < 8; ++c) pd[c] = 0.f;
        for (int i = lane; i < cnt; i += 64) {
#pragma unroll
            for (int c = 0; c < 8; ++c) {
                float ex = __expf(ew[c * CAP + i] - mx[c]);
                ew[c * CAP + i] = ex;
                pd[c] += ex;
            }
        }
#pragma unroll
        for (int off = 32; off > 0; off >>= 1)
#pragma unroll
            for (int c = 0; c < 8; ++c) pd[c] += __shfl_xor(pd[c], off);
#pragma unroll
        for (int c = 0; c < 8; ++c) den[c] += pd[c];

        // phase C: gather with unnormalized weights (2 edges/iter, 4 loads in flight)
        int i = 0;
        for (; i + 2 <= cnt; i += 2) {
            int o0 = colw[i], o1 = colw[i + 1];
            float wA0 = ew[hsel * CAP + i],       wB0 = ew[(4 + hsel) * CAP + i];
            float wA1 = ew[hsel * CAP + i + 1],   wB1 = ew[(4 + hsel) * CAP + i + 1];
            ushort4 v00 = *reinterpret_cast<const ushort4*>(hb0 + o0);
            ushort4 v01 = *reinterpret_cast<const ushort4*>(hb1 + o0);
            ushort4 v10 = *reinterpret_cast<const ushort4*>(hb0 + o1);
            ushort4 v11 = *reinterpret_cast<const ushort4*>(hb1 + o1);
            acc[0] = fmaf(h2f(v00.x), wA0, acc[0]); acc[1] = fmaf(h2f(v00.y), wA0, acc[1]);
            acc[2] = fmaf(h2f(v00.z), wA0, acc[2]); acc[3] = fmaf(h2f(v00.w), wA0, acc[3]);
            acc[4] = fmaf(h2f(v01.x), wB0, acc[4]); acc[5] = fmaf(h2f(v01.y), wB0, acc[5]);
            acc[6] = fmaf(h2f(v01.z), wB0, acc[6]); acc[7] = fmaf(h2f(v01.w), wB0, acc[7]);
            acc[0] = fmaf(h2f(v10.x), wA1, acc[0]); acc[1] = fmaf(h2f(v10.y), wA1, acc[1]);
            acc[2] = fmaf(h2f(v10.z), wA1, acc[2]); acc[3] = fmaf(h2f(v10.w), wA1, acc[3]);
            acc[4] = fmaf(h2f(v11.x), wB1, acc[4]); acc[5] = fmaf(h2f(v11.y), wB1, acc[5]);
            acc[6] = fmaf(h2f(v11.z), wB1, acc[6]); acc[7] = fmaf(h2f(v11.w), wB1, acc[7]);
        }
        for (; i < cnt; ++i) {
            int o = colw[i];
            float wA = ew[hsel * CAP + i], wB = ew[(4 + hsel) * CAP + i];
            ushort4 v0 = *reinterpret_cast<const ushort4*>(hb0 + o);
            ushort4 v1 = *reinterpret_cast<const ushort4*>(hb1 + o);
            acc[0] = fmaf(h2f(v0.x), wA, acc[0]); acc[1] = fmaf(h2f(v0.y), wA, acc[1]);
            acc[2] = fmaf(h2f(v0.z), wA, acc[2]); acc[3] = fmaf(h2f(v0.w), wA, acc[3]);
            acc[4] = fmaf(h2f(v1.x), wB, acc[4]); acc[5] = fmaf(h2f(v1.y), wB, acc[5]);
            acc[6] = fmaf(h2f(v1.z), wB, acc[6]); acc[7] = fmaf(h2f(v1.w), wB, acc[7]);
        }
    }

    // normalize + bias (+ELU) + store f16 both batches
    float4 bv = *reinterpret_cast<const float4*>(&bias[4 * lane]);
    float binv[4] = {bv.x, bv.y, bv.z, bv.w};
    float inv0 = 1.0f / den[hsel];
    float inv1 = 1.0f / den[4 + hsel];
    ushort4 o0, o1;
    float r;
    r = acc[0] * inv0 + binv[0]; if (do_elu && r < 0.f) r = expm1f(r); o0.x = f2h_bits(r);
    r = acc[1] * inv0 + binv[1]; if (do_elu && r < 0.f) r = expm1f(r); o0.y = f2h_bits(r);
    r = acc[2] * inv0 + binv[2]; if (do_elu && r < 0.f) r = expm1f(r); o0.z = f2h_bits(r);
    r = acc[3] * inv0 + binv[3]; if (do_elu && r < 0.f) r = expm1f(r); o0.w = f2h_bits(r);
    r = acc[4] * inv1 + binv[0]; if (do_elu && r < 0.f) r = expm1f(r); o1.x = f2h_bits(r);
    r = acc[5] * inv1 + binv[1]; if (do_elu && r < 0.f) r = expm1f(r); o1.y = f2h_bits(r);
    r = acc[6] * inv1 + binv[2]; if (do_elu && r < 0.f) r = expm1f(r); o1.z = f2h_bits(r);
    r = acc[7] * inv1 + binv[3]; if (do_elu && r < 0.f) r = expm1f(r); o1.w = f2h_bits(r);
    *reinterpret_cast<ushort4*>(&outh[(size_t)n * HC + 4 * lane]) = o0;
    *reinterpret_cast<ushort4*>(&outh[((size_t)NN + n) * HC + 4 * lane]) = o1;
}

// ---------------- launch ----------------

extern "C" void kernel_launch(void* const* d_in, const int* in_sizes, int n_in,
                              void* d_out, int out_size, void* d_ws, size_t ws_size,
                              hipStream_t stream) {
    const float* x      = (const float*)d_in[0];   // [2, NN, FIN]
    const int*   ei     = (const int*)d_in[1];     // [2, NE]
    const float* W1     = (const float*)d_in[2];   // [FIN, HC]
    const float* a_src1 = (const float*)d_in[3];
    const float* a_dst1 = (const float*)d_in[4];
    const float* b1     = (const float*)d_in[5];
    const float* W2     = (const float*)d_in[6];   // [HC, HC]
    const float* a_src2 = (const float*)d_in[7];
    const float* a_dst2 = (const float*)d_in[8];
    const float* b2     = (const float*)d_in[9];
    const float* Wf     = (const float*)d_in[10];  // [HC, CH]
    const float* bf     = (const float*)d_in[11];
    float* out = (float*)d_out;                    // [2, NN, CH]

    const int M2 = 2 * NN;                         // batch-fused rows
    float* ws = (float*)d_ws;
    float* Ssrc = ws;                              // M2*NH
    float* Sdst = Ssrc + (size_t)M2 * NH;          // M2*NH
    ushort_t* Hb16 = (ushort_t*)(Sdst + (size_t)M2 * NH);  // M2*HC f16 (gemm out)
    ushort_t* Ob16 = Hb16 + (size_t)M2 * HC;       // M2*HC f16 (agg out)
    ushort_t* Xb16 = Ob16 + (size_t)M2 * HC;       // M2*FIN f16
    ushort_t* Wt1  = Xb16 + (size_t)M2 * FIN;      // HC*FIN
    ushort_t* Wt2  = Wt1 + (size_t)HC * FIN;       // HC*HC
    ushort_t* Wtf  = Wt2 + (size_t)HC * HC;        // CH*HC
    int* counts = (int*)(Wtf + (size_t)CH * HC);
    int* rowptr = counts + NN;
    int* cursor = rowptr + (NN + 1);
    int* colidx = cursor + NN;                     // ETOT

    // ---- CSR build ----
    k_zero_i32<<<(NN + 255) / 256, 256, 0, stream>>>(counts, NN);
    k_hist<<<(ETOT + 255) / 256, 256, 0, stream>>>(ei, counts);
    k_scan<<<1, 1024, 0, stream>>>(counts, rowptr);
    k_copy_i32<<<(NN + 255) / 256, 256, 0, stream>>>(rowptr, cursor, NN);
    k_scatter<<<(ETOT + 255) / 256, 256, 0, stream>>>(ei, cursor, colidx);

    // ---- weight transpose + convert ----
    k_wt<<<(FIN * HC + 255) / 256, 256, 0, stream>>>(W1, Wt1, FIN, HC);
    k_wt<<<(HC * HC + 255) / 256, 256, 0, stream>>>(W2, Wt2, HC, HC);
    k_wt<<<(HC * CH + 255) / 256, 256, 0, stream>>>(Wf, Wtf, HC, CH);

    // ---- input convert (both batches at once) ----
    k_f2h<<<(M2 * FIN / 4 + 255) / 256, 256, 0, stream>>>(x, Xb16, M2 * FIN);

    const int gM = M2 / 64;  // 625
    // layer 1
    k_gemm_mfma<<<dim3(gM, HC / 64), 256, 0, stream>>>(Xb16, Wt1, Hb16, nullptr, nullptr, M2, FIN, HC);
    k_scores<<<(M2 + 3) / 4, 256, 0, stream>>>(Hb16, a_src1, a_dst1, Ssrc, Sdst);
    k_agg<<<NN / 4, 256, 0, stream>>>(Hb16, Ssrc, Sdst, rowptr, colidx, b1, Ob16, 1);
    // layer 2
    k_gemm_mfma<<<dim3(gM, HC / 64), 256, 0, stream>>>(Ob16, Wt2, Hb16, nullptr, nullptr, M2, HC, HC);
    k_scores<<<(M2 + 3) / 4, 256, 0, stream>>>(Hb16, a_src2, a_dst2, Ssrc, Sdst);
    k_agg<<<NN / 4, 256, 0, stream>>>(Hb16, Ssrc, Sdst, rowptr, colidx, b2, Ob16, 0);
    // final projection (f16 MFMA, f32 out + bias)
    k_gemm_mfma<<<dim3(gM, CH / 64), 256, 0, stream>>>(Ob16, Wtf, nullptr, out, bf, M2, HC, CH);
}